// Round 3
// baseline (243.628 us; speedup 1.0000x reference)
//
#include <hip/hip_runtime.h>

#define BB 4096
#define TT 512
#define HH 32

typedef _Float16 half8 __attribute__((ext_vector_type(8)));  // MFMA A/B frag (4 VGPRs)
typedef _Float16 h2    __attribute__((ext_vector_type(2)));  // packed f16 pair
typedef float    f32x4 __attribute__((ext_vector_type(4)));  // MFMA C/D
typedef unsigned int uint32;

#define MFMA16F(a, b, c) __builtin_amdgcn_mfma_f32_16x16x32_f16((a), (b), (c), 0, 0, 0)

union frag_u { half8 h8; h2 p[4]; };
union h2u { h2 h; uint32 u; };

// v_cvt_pkrtz_f16_f32 returns a __fp16 ext-vector; bit-cast to _Float16 vector.
__device__ __forceinline__ h2 pkrtz(float a, float b) {
    auto r = __builtin_amdgcn_cvt_pkrtz(a, b);
    union { decltype(r) i; h2 o; } u;
    u.i = r;
    return u.o;
}

// f16x2 broadcast constant as uint32 bits (constant-folded).
__device__ __forceinline__ uint32 h2c(float f) {
    union { _Float16 h; unsigned short s; } c;
    c.h = (_Float16)f;
    return (uint32)c.s * 0x10001u;
}

// tanh(v) ~= v * P(v^2), P quintic on |v|<=2.75 (max err ~2e-3).
// Same coefficients / op order / f16 rounding as the verified round-0 kernel,
// but emitted as GUARANTEED packed VOP3P (v_pk_*) via inline asm.
// Theory: __builtin_elementwise_* was scalarizing to 2x v_fma_f16 per op
// (VALUBusy says ~225 instr/step vs ~94 hand-counted packed), and the kernel
// is VALU-issue-bound on a single SIMD.
__device__ __forceinline__ h2 tanh_h2(h2 vin) {
    const uint32 HI = h2c(2.75f),      LO = h2c(-2.75f);
    const uint32 K5 = h2c(-0.00006405f), K4 = h2c(0.0016113f);
    const uint32 K3 = h2c(-0.0163448f),  K2 = h2c(0.0889744f);
    const uint32 K1 = h2c(-0.3098016f),  K0 = h2c(0.9976293f);
    h2u v; v.h = vin;
    uint32 r, u, t;
    asm("v_pk_min_f16 %0, %1, %2" : "=v"(r) : "v"(v.u), "v"(HI));
    asm("v_pk_max_f16 %0, %1, %2" : "=v"(r) : "v"(r), "v"(LO));
    asm("v_pk_mul_f16 %0, %1, %2" : "=v"(u) : "v"(r), "v"(r));
    asm("v_pk_fma_f16 %0, %1, %2, %3" : "=v"(t) : "v"(u), "v"(K5), "v"(K4));
    asm("v_pk_fma_f16 %0, %1, %2, %3" : "=v"(t) : "v"(u), "v"(t), "v"(K3));
    asm("v_pk_fma_f16 %0, %1, %2, %3" : "=v"(t) : "v"(u), "v"(t), "v"(K2));
    asm("v_pk_fma_f16 %0, %1, %2, %3" : "=v"(t) : "v"(u), "v"(t), "v"(K1));
    asm("v_pk_fma_f16 %0, %1, %2, %3" : "=v"(t) : "v"(u), "v"(t), "v"(K0));
    asm("v_pk_mul_f16 %0, %1, %2" : "=v"(r) : "v"(r), "v"(t));
    h2u o; o.u = r;
    return o.h;
}

// D = W @ H^T per step, M = h'-rows (2 tiles of 16), N = 16 batches.
// Row permutation pi_t(m) = 8*(m>>2) + (m&3) + 4t makes the C/D output layout
// equal the B-operand layout of the next matvec -> recurrence stays in registers.
// One-step skew retained (layer 1 lags layer 0 by one step inside the wave).
__global__ __launch_bounds__(64) void rnn2_mfma(
    const float* __restrict__ x,      // [B, T]
    const float* __restrict__ hstate, // [2, B, H]
    const float* __restrict__ Wih0,   // [H, 1]
    const float* __restrict__ Whh0,   // [H, H]
    const float* __restrict__ bih0,   // [H]
    const float* __restrict__ bhh0,   // [H]
    const float* __restrict__ Wih1,   // [H, H]
    const float* __restrict__ Whh1,   // [H, H]
    const float* __restrict__ bih1,   // [H]
    const float* __restrict__ bhh1,   // [H]
    const float* __restrict__ Wfc,    // [1, H]
    const float* __restrict__ bfc,    // [1]
    float* __restrict__ out)          // [B] pred ++ [2,B,H] h_new
{
    const int l = threadIdx.x;   // 0..63
    const int q = l >> 4;        // lane quad -> k-offset 8q
    const int n = l & 15;        // batch-in-tile / matrix row m
    const int b = blockIdx.x * 16 + n;

    // ---- weight A-fragments (f16), permuted rows ----
    const int r0 = 8 * (n >> 2) + (n & 3);
    half8 A0[2], A1i[2], A1h[2];
#pragma unroll
    for (int t = 0; t < 2; ++t) {
        const int row = r0 + 4 * t;
        const float* p0 = Whh0 + row * HH + q * 8;
        const float* p1 = Wih1 + row * HH + q * 8;
        const float* p2 = Whh1 + row * HH + q * 8;
        frag_u f0, f1, f2;
#pragma unroll
        for (int jj = 0; jj < 4; ++jj) {
            f0.p[jj] = h2{(_Float16)p0[2 * jj], (_Float16)p0[2 * jj + 1]};
            f1.p[jj] = h2{(_Float16)p1[2 * jj], (_Float16)p1[2 * jj + 1]};
            f2.p[jj] = h2{(_Float16)p2[2 * jj], (_Float16)p2[2 * jj + 1]};
        }
        A0[t] = f0.h8; A1i[t] = f1.h8; A1h[t] = f2.h8;
    }

    // ---- per-lane constants over j=0..7 (h' = 8q + j) ----
    float wxs[8], b0s[8], wfc8[8];
#pragma unroll
    for (int j = 0; j < 8; ++j) {
        const int hh = 8 * q + j;
        wxs[j]  = Wih0[hh];
        b0s[j]  = bih0[hh] + bhh0[hh];
        wfc8[j] = Wfc[hh];
    }
    f32x4 c1t0, c1t1;
#pragma unroll
    for (int r = 0; r < 4; ++r) {
        c1t0[r] = bih1[8 * q + r] + bhh1[8 * q + r];
        c1t1[r] = bih1[8 * q + 4 + r] + bhh1[8 * q + 4 + r];
    }

    // ---- initial h state as f16 B-fragments ----
    frag_u hb0, hb1;
    {
        const float* p0 = hstate + b * HH + 8 * q;
        const float* p1 = hstate + BB * HH + b * HH + 8 * q;
#pragma unroll
        for (int jj = 0; jj < 4; ++jj) {
            hb0.p[jj] = h2{(_Float16)p0[2 * jj], (_Float16)p0[2 * jj + 1]};
            hb1.p[jj] = h2{(_Float16)p1[2 * jj], (_Float16)p1[2 * jj + 1]};
        }
    }

    f32x4 dbp0, dbp1;   // pending bias1 + Whh1 . h1(s-2)

    const float4* xp = (const float4*)(x + (size_t)b * TT);
    float4 xc = xp[0];

    // ---- prologue: layer-0 step 0, and pending db for layer-1 step 0 ----
    {
        f32x4 c00, c01;
#pragma unroll
        for (int r = 0; r < 4; ++r) {
            c00[r] = fmaf(wxs[r], xc.x, b0s[r]);
            c01[r] = fmaf(wxs[4 + r], xc.x, b0s[4 + r]);
        }
        f32x4 d00 = MFMA16F(A0[0], hb0.h8, c00);
        f32x4 d01 = MFMA16F(A0[1], hb0.h8, c01);
        dbp0 = MFMA16F(A1h[0], hb1.h8, c1t0);
        dbp1 = MFMA16F(A1h[1], hb1.h8, c1t1);
        hb0.p[0] = tanh_h2(pkrtz(d00[0], d00[1]));
        hb0.p[1] = tanh_h2(pkrtz(d00[2], d00[3]));
        hb0.p[2] = tanh_h2(pkrtz(d01[0], d01[1]));
        hb0.p[3] = tanh_h2(pkrtz(d01[2], d01[3]));
    }

    // One pipeline step: enter with hb0=h0(s-1), hb1=h1(s-2), dbp=b1+Whh1.h1(s-2).
    // Computes h1(s-1) and h0(s); refills dbp with Whh1.h1(s-1).
#define STEP(XT)                                                              \
    {                                                                         \
        f32x4 d10 = MFMA16F(A1i[0], hb0.h8, dbp0);                            \
        f32x4 d11 = MFMA16F(A1i[1], hb0.h8, dbp1);                            \
        f32x4 c00, c01;                                                       \
        _Pragma("unroll")                                                     \
        for (int r = 0; r < 4; ++r) {                                         \
            c00[r] = fmaf(wxs[r], (XT), b0s[r]);                              \
            c01[r] = fmaf(wxs[4 + r], (XT), b0s[4 + r]);                      \
        }                                                                     \
        f32x4 d00 = MFMA16F(A0[0], hb0.h8, c00);                              \
        f32x4 d01 = MFMA16F(A0[1], hb0.h8, c01);                              \
        hb1.p[0] = tanh_h2(pkrtz(d10[0], d10[1]));                            \
        hb1.p[1] = tanh_h2(pkrtz(d10[2], d10[3]));                            \
        hb1.p[2] = tanh_h2(pkrtz(d11[0], d11[1]));                            \
        hb1.p[3] = tanh_h2(pkrtz(d11[2], d11[3]));                            \
        dbp0 = MFMA16F(A1h[0], hb1.h8, c1t0);                                 \
        dbp1 = MFMA16F(A1h[1], hb1.h8, c1t1);                                 \
        hb0.p[0] = tanh_h2(pkrtz(d00[0], d00[1]));                            \
        hb0.p[1] = tanh_h2(pkrtz(d00[2], d00[3]));                            \
        hb0.p[2] = tanh_h2(pkrtz(d01[0], d01[1]));                            \
        hb0.p[3] = tanh_h2(pkrtz(d01[2], d01[3]));                            \
    }

    // main loop: k = 0..126 handles s = 4k+1 .. 4k+4
    for (int k = 0; k < TT / 4 - 1; ++k) {
        float4 xn = xp[k + 1];
        STEP(xc.y);
        STEP(xc.z);
        STEP(xc.w);
        STEP(xn.x);
        xc = xn;
    }
    // s = 509, 510, 511
    STEP(xc.y);
    STEP(xc.z);
    STEP(xc.w);

    // tail: layer-1 step 511
    {
        f32x4 d10 = MFMA16F(A1i[0], hb0.h8, dbp0);
        f32x4 d11 = MFMA16F(A1i[1], hb0.h8, dbp1);
        hb1.p[0] = tanh_h2(pkrtz(d10[0], d10[1]));
        hb1.p[1] = tanh_h2(pkrtz(d10[2], d10[3]));
        hb1.p[2] = tanh_h2(pkrtz(d11[0], d11[1]));
        hb1.p[3] = tanh_h2(pkrtz(d11[2], d11[3]));
    }

    // ---- epilogue ----
    float hf0[8], hf1[8];
#pragma unroll
    for (int jj = 0; jj < 4; ++jj) {
        hf0[2 * jj]     = (float)hb0.p[jj].x;
        hf0[2 * jj + 1] = (float)hb0.p[jj].y;
        hf1[2 * jj]     = (float)hb1.p[jj].x;
        hf1[2 * jj + 1] = (float)hb1.p[jj].y;
    }
    float p = 0.f;
#pragma unroll
    for (int j = 0; j < 8; ++j) p = fmaf(wfc8[j], hf1[j], p);
    p += __shfl_xor(p, 16);
    p += __shfl_xor(p, 32);
    if (q == 0) out[b] = p + bfc[0];

#pragma unroll
    for (int j = 0; j < 8; ++j) {
        out[BB + b * HH + 8 * q + j]           = hf0[j];
        out[BB + BB * HH + b * HH + 8 * q + j] = hf1[j];
    }
}

extern "C" void kernel_launch(void* const* d_in, const int* in_sizes, int n_in,
                              void* d_out, int out_size, void* d_ws, size_t ws_size,
                              hipStream_t stream) {
    const float* x      = (const float*)d_in[0];
    const float* hstate = (const float*)d_in[1];
    const float* Wih0   = (const float*)d_in[2];
    const float* Whh0   = (const float*)d_in[3];
    const float* bih0   = (const float*)d_in[4];
    const float* bhh0   = (const float*)d_in[5];
    const float* Wih1   = (const float*)d_in[6];
    const float* Whh1   = (const float*)d_in[7];
    const float* bih1   = (const float*)d_in[8];
    const float* bhh1   = (const float*)d_in[9];
    const float* Wfc    = (const float*)d_in[10];
    const float* bfc    = (const float*)d_in[11];
    float* out = (float*)d_out;

    dim3 grid(BB / 16);  // 256 blocks x 1 wave, one 16-batch tile each
    dim3 block(64);
    hipLaunchKernelGGL(rnn2_mfma, grid, block, 0, stream,
                       x, hstate, Wih0, Whh0, bih0, bhh0,
                       Wih1, Whh1, bih1, bhh1, Wfc, bfc, out);
}

// Round 4
// 206.626 us; speedup vs baseline: 1.1791x; 1.1791x over previous
//
#include <hip/hip_runtime.h>

#define BB 4096
#define TT 512
#define HH 32

typedef _Float16 half8 __attribute__((ext_vector_type(8)));  // MFMA A/B frag (4 VGPRs)
typedef _Float16 half4 __attribute__((ext_vector_type(4)));  // half fragment (8B)
typedef _Float16 h2    __attribute__((ext_vector_type(2)));  // packed f16 pair
typedef float    f32x4 __attribute__((ext_vector_type(4)));  // MFMA C/D

#define MFMA16F(a, b, c) __builtin_amdgcn_mfma_f32_16x16x32_f16((a), (b), (c), 0, 0, 0)

union frag_u { half8 h8; h2 p[4]; };
union h4u   { half4 v;  h2 p[2]; };

__device__ __forceinline__ h2 pkrtz(float a, float b) {
    auto r = __builtin_amdgcn_cvt_pkrtz(a, b);
    union { decltype(r) i; h2 o; } u;
    u.i = r;
    return u.o;
}

// tanh(v) ~= v * P(v^2), P quintic on |v|<=2.75 (max err ~2e-3).
// EXACT round-0 version (builtins — already emit packed VOP3P; round-3 proved
// forcing asm only hurts scheduling).
__device__ __forceinline__ h2 tanh_h2(h2 v) {
    const h2 LO = {(_Float16)(-2.75f), (_Float16)(-2.75f)};
    const h2 HI = {(_Float16)(2.75f), (_Float16)(2.75f)};
    const h2 C0 = {(_Float16)(0.9976293f), (_Float16)(0.9976293f)};
    const h2 C1 = {(_Float16)(-0.3098016f), (_Float16)(-0.3098016f)};
    const h2 C2 = {(_Float16)(0.0889744f), (_Float16)(0.0889744f)};
    const h2 C3 = {(_Float16)(-0.0163448f), (_Float16)(-0.0163448f)};
    const h2 C4 = {(_Float16)(0.0016113f), (_Float16)(0.0016113f)};
    const h2 C5 = {(_Float16)(-0.00006405f), (_Float16)(-0.00006405f)};
    v = __builtin_elementwise_min(v, HI);
    v = __builtin_elementwise_max(v, LO);
    h2 u = v * v;
    h2 t = __builtin_elementwise_fma(u, C5, C4);
    t = __builtin_elementwise_fma(u, t, C3);
    t = __builtin_elementwise_fma(u, t, C2);
    t = __builtin_elementwise_fma(u, t, C1);
    t = __builtin_elementwise_fma(u, t, C0);
    return v * t;
}

// M-SPLIT: wave `wid` owns MFMA tile t=wid (rows pi(m)+4*wid) of all three
// per-step matvecs.  Per-wave work halves; runs on 2 SIMDs per CU.
// Bit-identical to the verified single-wave kernel: identical MFMA/tanh inputs,
// halves reassembled via positioned LDS writes (own 8B at +8*wid) and a full
// 16B read after one __syncthreads per step.  2-slot ring: slot s&1; a slot's
// reuse is separated by two barriers -> race-free by construction.
__global__ __launch_bounds__(128) void rnn2_mfma_ms(
    const float* __restrict__ x,      // [B, T]
    const float* __restrict__ hstate, // [2, B, H]
    const float* __restrict__ Wih0,   // [H, 1]
    const float* __restrict__ Whh0,   // [H, H]
    const float* __restrict__ bih0,   // [H]
    const float* __restrict__ bhh0,   // [H]
    const float* __restrict__ Wih1,   // [H, H]
    const float* __restrict__ Whh1,   // [H, H]
    const float* __restrict__ bih1,   // [H]
    const float* __restrict__ bhh1,   // [H]
    const float* __restrict__ Wfc,    // [1, H]
    const float* __restrict__ bfc,    // [1]
    float* __restrict__ out)          // [B] pred ++ [2,B,H] h_new
{
    const int tid = threadIdx.x;
    const int l = tid & 63;
    const int wid = __builtin_amdgcn_readfirstlane(tid >> 6); // tile index 0/1
    const int q = l >> 4;
    const int n = l & 15;
    const int b = blockIdx.x * 16 + n;
    const bool w0 = (wid == 0);

    __shared__ half8 xb[2][2][64];    // [layer][slot][lane] full fragments

    // ---- A-fragments for tile t=wid only: row = pi(m) + 4*wid ----
    const int r0 = 8 * (n >> 2) + (n & 3);
    const int row = r0 + 4 * wid;
    half8 A0w, A1iw, A1hw;
    {
        const float* p0 = Whh0 + row * HH + q * 8;
        const float* p1 = Wih1 + row * HH + q * 8;
        const float* p2 = Whh1 + row * HH + q * 8;
        frag_u f0, f1, f2;
#pragma unroll
        for (int jj = 0; jj < 4; ++jj) {
            f0.p[jj] = h2{(_Float16)p0[2 * jj], (_Float16)p0[2 * jj + 1]};
            f1.p[jj] = h2{(_Float16)p1[2 * jj], (_Float16)p1[2 * jj + 1]};
            f2.p[jj] = h2{(_Float16)p2[2 * jj], (_Float16)p2[2 * jj + 1]};
        }
        A0w = f0.h8; A1iw = f1.h8; A1hw = f2.h8;
    }

    // ---- per-lane consts: C/D rows of tile wid are hh = 8q + 4*wid + r ----
    float wxs[4], b0s[4], wfc8[8];
    f32x4 c1tw;
#pragma unroll
    for (int r = 0; r < 4; ++r) {
        const int hh = 8 * q + 4 * wid + r;
        wxs[r]  = Wih0[hh];
        b0s[r]  = bih0[hh] + bhh0[hh];
        c1tw[r] = bih1[hh] + bhh1[hh];
    }
#pragma unroll
    for (int j = 0; j < 8; ++j) wfc8[j] = Wfc[8 * q + j];

    // ---- initial full h states (both waves, identical f32->f16 conversion) ----
    frag_u hb0, hb1i;
    {
        const float* p0 = hstate + (size_t)b * HH + 8 * q;
        const float* p1 = hstate + (size_t)BB * HH + (size_t)b * HH + 8 * q;
#pragma unroll
        for (int jj = 0; jj < 4; ++jj) {
            hb0.p[jj]  = h2{(_Float16)p0[2 * jj], (_Float16)p0[2 * jj + 1]};
            hb1i.p[jj] = h2{(_Float16)p1[2 * jj], (_Float16)p1[2 * jj + 1]};
        }
    }

    f32x4 dbp = MFMA16F(A1hw, hb1i.h8, c1tw);  // own half of b1 + Whh1.h1(-1)

    // positioned write pointers (loop-invariant): own 8B half at +8*wid
    half4* wp0s0 = (half4*)((char*)&xb[0][0][l] + 8 * wid);
    half4* wp0s1 = (half4*)((char*)&xb[0][1][l] + 8 * wid);
    half4* wp1s0 = (half4*)((char*)&xb[1][0][l] + 8 * wid);
    half4* wp1s1 = (half4*)((char*)&xb[1][1][l] + 8 * wid);

    const float4* xp = (const float4*)(x + (size_t)b * TT);
    float4 xc = xp[0];

    // ---- prologue: step 0 (layer 0 only), slot 0 ----
    {
        f32x4 c0;
#pragma unroll
        for (int r = 0; r < 4; ++r) c0[r] = fmaf(wxs[r], xc.x, b0s[r]);
        f32x4 d0 = MFMA16F(A0w, hb0.h8, c0);
        h4u ho;
        ho.p[0] = tanh_h2(pkrtz(d0[0], d0[1]));
        ho.p[1] = tanh_h2(pkrtz(d0[2], d0[3]));
        *wp0s0 = ho.v;
        __syncthreads();
        hb0.h8 = xb[0][0][l];                  // full h0(0)
    }

    // One step s (slot = s&1): entering with hb0 = h0(s-1) full,
    // dbp = own half of b1 + Whh1.h1(s-2).
    // Computes h1(s-1) half and h0(s) half; exchanges; refills dbp from full
    // h1(s-1).  WP1/WP0 are the slot's positioned write pointers.
#define STEPM(XT, SLOT, WP1, WP0)                                             \
    {                                                                         \
        f32x4 d1 = MFMA16F(A1iw, hb0.h8, dbp);                                \
        f32x4 c0;                                                             \
        _Pragma("unroll")                                                     \
        for (int r = 0; r < 4; ++r) c0[r] = fmaf(wxs[r], (XT), b0s[r]);       \
        f32x4 d0 = MFMA16F(A0w, hb0.h8, c0);                                  \
        h4u h1o;                                                              \
        h1o.p[0] = tanh_h2(pkrtz(d1[0], d1[1]));                              \
        h1o.p[1] = tanh_h2(pkrtz(d1[2], d1[3]));                              \
        *(WP1) = h1o.v;                                                       \
        h4u h0o;                                                              \
        h0o.p[0] = tanh_h2(pkrtz(d0[0], d0[1]));                              \
        h0o.p[1] = tanh_h2(pkrtz(d0[2], d0[3]));                              \
        *(WP0) = h0o.v;                                                       \
        __syncthreads();                                                      \
        frag_u h1f;                                                           \
        h1f.h8 = xb[1][SLOT][l];                                              \
        hb0.h8 = xb[0][SLOT][l];                                              \
        dbp = MFMA16F(A1hw, h1f.h8, c1tw);                                    \
    }

    // main loop: k = 0..126 handles s = 4k+1 .. 4k+4 (slots 1,0,1,0)
    for (int k = 0; k < TT / 4 - 1; ++k) {
        float4 xn = xp[k + 1];
        STEPM(xc.y, 1, wp1s1, wp0s1);
        STEPM(xc.z, 0, wp1s0, wp0s0);
        STEPM(xc.w, 1, wp1s1, wp0s1);
        STEPM(xn.x, 0, wp1s0, wp0s0);
        xc = xn;
    }
    // s = 509, 510, 511
    STEPM(xc.y, 1, wp1s1, wp0s1);
    STEPM(xc.z, 0, wp1s0, wp0s0);
    STEPM(xc.w, 1, wp1s1, wp0s1);

    // ---- tail: h1(511), slot 0 ----
    frag_u h1fin;
    {
        f32x4 d1 = MFMA16F(A1iw, hb0.h8, dbp);
        h4u h1o;
        h1o.p[0] = tanh_h2(pkrtz(d1[0], d1[1]));
        h1o.p[1] = tanh_h2(pkrtz(d1[2], d1[3]));
        *wp1s0 = h1o.v;
        __syncthreads();
        h1fin.h8 = xb[1][0][l];                // full h1(511)
    }

    // ---- epilogue: wave0 writes h0 plane; wave1 writes h1 plane + pred ----
    float hf0[8], hf1[8];
#pragma unroll
    for (int jj = 0; jj < 4; ++jj) {
        hf0[2 * jj]     = (float)hb0.p[jj].x;
        hf0[2 * jj + 1] = (float)hb0.p[jj].y;
        hf1[2 * jj]     = (float)h1fin.p[jj].x;
        hf1[2 * jj + 1] = (float)h1fin.p[jj].y;
    }
    if (w0) {
#pragma unroll
        for (int j = 0; j < 8; ++j)
            out[BB + (size_t)b * HH + 8 * q + j] = hf0[j];
    } else {
        float p = 0.f;
#pragma unroll
        for (int j = 0; j < 8; ++j) p = fmaf(wfc8[j], hf1[j], p);
        p += __shfl_xor(p, 16);
        p += __shfl_xor(p, 32);
        if (q == 0) out[b] = p + bfc[0];
#pragma unroll
        for (int j = 0; j < 8; ++j)
            out[BB + (size_t)BB * HH + (size_t)b * HH + 8 * q + j] = hf1[j];
    }
}

extern "C" void kernel_launch(void* const* d_in, const int* in_sizes, int n_in,
                              void* d_out, int out_size, void* d_ws, size_t ws_size,
                              hipStream_t stream) {
    const float* x      = (const float*)d_in[0];
    const float* hstate = (const float*)d_in[1];
    const float* Wih0   = (const float*)d_in[2];
    const float* Whh0   = (const float*)d_in[3];
    const float* bih0   = (const float*)d_in[4];
    const float* bhh0   = (const float*)d_in[5];
    const float* Wih1   = (const float*)d_in[6];
    const float* Whh1   = (const float*)d_in[7];
    const float* bih1   = (const float*)d_in[8];
    const float* bhh1   = (const float*)d_in[9];
    const float* Wfc    = (const float*)d_in[10];
    const float* bfc    = (const float*)d_in[11];
    float* out = (float*)d_out;

    dim3 grid(BB / 16);   // 256 blocks, one 16-batch tile each
    dim3 block(128);      // 2 waves: MFMA tile 0 / tile 1 (M-split)
    hipLaunchKernelGGL(rnn2_mfma_ms, grid, block, 0, stream,
                       x, hstate, Wih0, Whh0, bih0, bhh0,
                       Wih1, Whh1, bih1, bhh1, Wfc, bfc, out);
}

// Round 5
// 204.621 us; speedup vs baseline: 1.1906x; 1.0098x over previous
//
#include <hip/hip_runtime.h>

#define BB 4096
#define TT 512
#define HH 32

typedef _Float16 half8 __attribute__((ext_vector_type(8)));  // MFMA A/B frag (4 VGPRs)
typedef _Float16 half4 __attribute__((ext_vector_type(4)));  // half fragment (8B)
typedef _Float16 h2    __attribute__((ext_vector_type(2)));  // packed f16 pair
typedef float    f32x4 __attribute__((ext_vector_type(4)));  // MFMA C/D

#define MFMA16F(a, b, c) __builtin_amdgcn_mfma_f32_16x16x32_f16((a), (b), (c), 0, 0, 0)

union frag_u { half8 h8; h2 p[4]; };
union h4u   { half4 v;  h2 p[2]; };

__device__ __forceinline__ h2 pkrtz(float a, float b) {
    auto r = __builtin_amdgcn_cvt_pkrtz(a, b);
    union { decltype(r) i; h2 o; } u;
    u.i = r;
    return u.o;
}

// tanh(v) ~= v * P(v^2), P quintic on |v|<=2.75 (max err ~2e-3).
// EXACT round-0 builtin version (already packed VOP3P).
__device__ __forceinline__ h2 tanh_h2(h2 v) {
    const h2 LO = {(_Float16)(-2.75f), (_Float16)(-2.75f)};
    const h2 HI = {(_Float16)(2.75f), (_Float16)(2.75f)};
    const h2 C0 = {(_Float16)(0.9976293f), (_Float16)(0.9976293f)};
    const h2 C1 = {(_Float16)(-0.3098016f), (_Float16)(-0.3098016f)};
    const h2 C2 = {(_Float16)(0.0889744f), (_Float16)(0.0889744f)};
    const h2 C3 = {(_Float16)(-0.0163448f), (_Float16)(-0.0163448f)};
    const h2 C4 = {(_Float16)(0.0016113f), (_Float16)(0.0016113f)};
    const h2 C5 = {(_Float16)(-0.00006405f), (_Float16)(-0.00006405f)};
    v = __builtin_elementwise_min(v, HI);
    v = __builtin_elementwise_max(v, LO);
    h2 u = v * v;
    h2 t = __builtin_elementwise_fma(u, C5, C4);
    t = __builtin_elementwise_fma(u, t, C3);
    t = __builtin_elementwise_fma(u, t, C2);
    t = __builtin_elementwise_fma(u, t, C1);
    t = __builtin_elementwise_fma(u, t, C0);
    return v * t;
}

// LDS-only barrier: lgkmcnt(0) drain (makes our ds_write visible) + s_barrier.
// Deliberately does NOT drain vmcnt: the x prefetch (wave-private HBM load)
// stays in flight across barriers.  __syncthreads' vmcnt(0) drain was putting
// the x-load latency on every step's barrier path in round 4 (672 cyc/step).
// Memory-clobber asm on both sides pins LDS ops to their side of the barrier.
#define XBAR()                                                    \
    do {                                                          \
        asm volatile("s_waitcnt lgkmcnt(0)" ::: "memory");        \
        __builtin_amdgcn_s_barrier();                             \
        asm volatile("" ::: "memory");                            \
    } while (0)

// Hybrid split: wave w computes its OWN half (tile t=w) of layer-0 exactly as
// the verified round-4 M-split, and DUPLICATES the full layer-1 computation
// (bit-identical in both waves; round-0's exact MFMA/tanh sequence).  Only h0
// halves cross LDS.  Post-barrier chain is just read -> d0 -> tanh -> write;
// the duplicated h1 tanh + dbp refill issues inside the ds_read latency shadow.
// SoA half-arrays make both the b64 write and b64 reads contiguous (no bank
// conflicts, round 4 had 2.1M).
__global__ __launch_bounds__(128) void rnn2_mfma_hs(
    const float* __restrict__ x,      // [B, T]
    const float* __restrict__ hstate, // [2, B, H]
    const float* __restrict__ Wih0,   // [H, 1]
    const float* __restrict__ Whh0,   // [H, H]
    const float* __restrict__ bih0,   // [H]
    const float* __restrict__ bhh0,   // [H]
    const float* __restrict__ Wih1,   // [H, H]
    const float* __restrict__ Whh1,   // [H, H]
    const float* __restrict__ bih1,   // [H]
    const float* __restrict__ bhh1,   // [H]
    const float* __restrict__ Wfc,    // [1, H]
    const float* __restrict__ bfc,    // [1]
    float* __restrict__ out)          // [B] pred ++ [2,B,H] h_new
{
    const int tid = threadIdx.x;
    const int l = tid & 63;
    const int wid = __builtin_amdgcn_readfirstlane(tid >> 6); // own tile 0/1
    const int q = l >> 4;
    const int n = l & 15;
    const int b = blockIdx.x * 16 + n;
    const bool w0 = (wid == 0);

    __shared__ half4 xbH[2][2][64];   // [tile][slot][lane], 8B each: SoA halves

    // ---- weight fragments: full layer-1 (both tiles), own layer-0 tile ----
    const int r0 = 8 * (n >> 2) + (n & 3);
    half8 A1i[2], A1h[2];
#pragma unroll
    for (int t = 0; t < 2; ++t) {
        const int row = r0 + 4 * t;
        const float* p1 = Wih1 + row * HH + q * 8;
        const float* p2 = Whh1 + row * HH + q * 8;
        frag_u f1, f2;
#pragma unroll
        for (int jj = 0; jj < 4; ++jj) {
            f1.p[jj] = h2{(_Float16)p1[2 * jj], (_Float16)p1[2 * jj + 1]};
            f2.p[jj] = h2{(_Float16)p2[2 * jj], (_Float16)p2[2 * jj + 1]};
        }
        A1i[t] = f1.h8; A1h[t] = f2.h8;
    }
    half8 A0w;
    {
        const int row = r0 + 4 * wid;
        const float* p0 = Whh0 + row * HH + q * 8;
        frag_u f0;
#pragma unroll
        for (int jj = 0; jj < 4; ++jj)
            f0.p[jj] = h2{(_Float16)p0[2 * jj], (_Float16)p0[2 * jj + 1]};
        A0w = f0.h8;
    }

    // ---- per-lane consts: own tile's x-inject; full layer-1 bias ----
    float wxs[4], b0s[4], wfc8[8];
#pragma unroll
    for (int r = 0; r < 4; ++r) {
        const int hh = 8 * q + 4 * wid + r;
        wxs[r] = Wih0[hh];
        b0s[r] = bih0[hh] + bhh0[hh];
    }
    f32x4 c1t0, c1t1;
#pragma unroll
    for (int r = 0; r < 4; ++r) {
        c1t0[r] = bih1[8 * q + r] + bhh1[8 * q + r];
        c1t1[r] = bih1[8 * q + 4 + r] + bhh1[8 * q + 4 + r];
    }
#pragma unroll
    for (int j = 0; j < 8; ++j) wfc8[j] = Wfc[8 * q + j];

    // ---- initial full h states (identical conversion in both waves) ----
    frag_u hb0, hb1;
    {
        const float* p0 = hstate + (size_t)b * HH + 8 * q;
        const float* p1 = hstate + (size_t)BB * HH + (size_t)b * HH + 8 * q;
#pragma unroll
        for (int jj = 0; jj < 4; ++jj) {
            hb0.p[jj] = h2{(_Float16)p0[2 * jj], (_Float16)p0[2 * jj + 1]};
            hb1.p[jj] = h2{(_Float16)p1[2 * jj], (_Float16)p1[2 * jj + 1]};
        }
    }

    f32x4 dbp0 = MFMA16F(A1h[0], hb1.h8, c1t0);  // b1 + Whh1 . h1(-1), full
    f32x4 dbp1 = MFMA16F(A1h[1], hb1.h8, c1t1);

    const float4* xp = (const float4*)(x + (size_t)b * TT);
    float4 xc = xp[0];

    // ---- prologue: step 0 (own h0(0) half), slot 0 ----
    {
        f32x4 c0;
#pragma unroll
        for (int r = 0; r < 4; ++r) c0[r] = fmaf(wxs[r], xc.x, b0s[r]);
        f32x4 d0 = MFMA16F(A0w, hb0.h8, c0);
        h4u ho;
        ho.p[0] = tanh_h2(pkrtz(d0[0], d0[1]));
        ho.p[1] = tanh_h2(pkrtz(d0[2], d0[3]));
        xbH[wid][0][l] = ho.v;
        XBAR();
        h4u lo, hi;
        lo.v = xbH[0][0][l];
        hi.v = xbH[1][0][l];
        hb0.p[0] = lo.p[0]; hb0.p[1] = lo.p[1];
        hb0.p[2] = hi.p[0]; hb0.p[3] = hi.p[1];
    }

    // One step s (slot = s&1).  Entering: hb0 = h0(s-1) full, dbp = full
    // b1 + Whh1.h1(s-2).  Computes h1(s-1) full (duplicated) and own half of
    // h0(s); exchanges h0; h1 tanh + dbp refill sit in the read shadow.
#define STEPB(XT, SLOT)                                                       \
    {                                                                         \
        f32x4 d10 = MFMA16F(A1i[0], hb0.h8, dbp0);                            \
        f32x4 d11 = MFMA16F(A1i[1], hb0.h8, dbp1);                            \
        f32x4 c0;                                                             \
        _Pragma("unroll")                                                     \
        for (int r = 0; r < 4; ++r) c0[r] = fmaf(wxs[r], (XT), b0s[r]);       \
        f32x4 d0 = MFMA16F(A0w, hb0.h8, c0);                                  \
        h4u ho;                                                               \
        ho.p[0] = tanh_h2(pkrtz(d0[0], d0[1]));                               \
        ho.p[1] = tanh_h2(pkrtz(d0[2], d0[3]));                               \
        xbH[wid][SLOT][l] = ho.v;                                             \
        XBAR();                                                               \
        h4u lo, hi;                                                           \
        lo.v = xbH[0][SLOT][l];                                               \
        hi.v = xbH[1][SLOT][l];                                               \
        hb1.p[0] = tanh_h2(pkrtz(d10[0], d10[1]));                            \
        hb1.p[1] = tanh_h2(pkrtz(d10[2], d10[3]));                            \
        hb1.p[2] = tanh_h2(pkrtz(d11[0], d11[1]));                            \
        hb1.p[3] = tanh_h2(pkrtz(d11[2], d11[3]));                            \
        dbp0 = MFMA16F(A1h[0], hb1.h8, c1t0);                                 \
        dbp1 = MFMA16F(A1h[1], hb1.h8, c1t1);                                 \
        hb0.p[0] = lo.p[0]; hb0.p[1] = lo.p[1];                               \
        hb0.p[2] = hi.p[0]; hb0.p[3] = hi.p[1];                               \
    }

    // main loop: k = 0..126 handles s = 4k+1 .. 4k+4 (slots 1,0,1,0)
    for (int k = 0; k < TT / 4 - 1; ++k) {
        float4 xn = xp[k + 1];
        STEPB(xc.y, 1);
        STEPB(xc.z, 0);
        STEPB(xc.w, 1);
        STEPB(xn.x, 0);
        xc = xn;
    }
    // s = 509, 510, 511
    STEPB(xc.y, 1);
    STEPB(xc.z, 0);
    STEPB(xc.w, 1);

    // ---- tail: h1(511) = tanh(Wih1 . h0(511) + dbp), both waves ----
    {
        f32x4 d10 = MFMA16F(A1i[0], hb0.h8, dbp0);
        f32x4 d11 = MFMA16F(A1i[1], hb0.h8, dbp1);
        hb1.p[0] = tanh_h2(pkrtz(d10[0], d10[1]));
        hb1.p[1] = tanh_h2(pkrtz(d10[2], d10[3]));
        hb1.p[2] = tanh_h2(pkrtz(d11[0], d11[1]));
        hb1.p[3] = tanh_h2(pkrtz(d11[2], d11[3]));
    }

    // ---- epilogue: wave0 stores h0(511) full; wave1 stores h1(511) + pred ----
    float hf0[8], hf1[8];
#pragma unroll
    for (int jj = 0; jj < 4; ++jj) {
        hf0[2 * jj]     = (float)hb0.p[jj].x;
        hf0[2 * jj + 1] = (float)hb0.p[jj].y;
        hf1[2 * jj]     = (float)hb1.p[jj].x;
        hf1[2 * jj + 1] = (float)hb1.p[jj].y;
    }
    if (w0) {
#pragma unroll
        for (int j = 0; j < 8; ++j)
            out[BB + (size_t)b * HH + 8 * q + j] = hf0[j];
    } else {
        float p = 0.f;
#pragma unroll
        for (int j = 0; j < 8; ++j) p = fmaf(wfc8[j], hf1[j], p);
        p += __shfl_xor(p, 16);
        p += __shfl_xor(p, 32);
        if (q == 0) out[b] = p + bfc[0];
#pragma unroll
        for (int j = 0; j < 8; ++j)
            out[BB + (size_t)BB * HH + (size_t)b * HH + 8 * q + j] = hf1[j];
    }
}

extern "C" void kernel_launch(void* const* d_in, const int* in_sizes, int n_in,
                              void* d_out, int out_size, void* d_ws, size_t ws_size,
                              hipStream_t stream) {
    const float* x      = (const float*)d_in[0];
    const float* hstate = (const float*)d_in[1];
    const float* Wih0   = (const float*)d_in[2];
    const float* Whh0   = (const float*)d_in[3];
    const float* bih0   = (const float*)d_in[4];
    const float* bhh0   = (const float*)d_in[5];
    const float* Wih1   = (const float*)d_in[6];
    const float* Whh1   = (const float*)d_in[7];
    const float* bih1   = (const float*)d_in[8];
    const float* bhh1   = (const float*)d_in[9];
    const float* Wfc    = (const float*)d_in[10];
    const float* bfc    = (const float*)d_in[11];
    float* out = (float*)d_out;

    dim3 grid(BB / 16);   // 256 blocks, one 16-batch tile each
    dim3 block(128);      // 2 waves: h0 halves exchanged, layer-1 duplicated
    hipLaunchKernelGGL(rnn2_mfma_hs, grid, block, 0, stream,
                       x, hstate, Wih0, Whh0, bih0, bhh0,
                       Wih1, Whh1, bih1, bhh1, Wfc, bfc, out);
}